// Round 19
// baseline (244.196 us; speedup 1.0000x reference)
//
#include <hip/hip_runtime.h>
#include <hip/hip_bf16.h>

// MemoryEfficientMultiheadAttention: chunked (block-diagonal) MHA.
// S=4096, B=4, D=1024, H=16, dk=64, CHUNK=256.
// cvt(weights) -> fused QKV GEMM (8-phase 256x256, 16 waves, 4 waves/SIMD,
// fused fp32->bf16 A staging, 1-deep A pipeline) -> flash attn (swapped
// QK^T, P-in-reg PV) -> out proj (16-wave 8-phase, 4 waves/SIMD).

namespace {

constexpr int kSeq = 4096, kB = 4, kDm = 1024, kNh = 16, kDk = 64, kChk = 256;
constexpr int kMr = kSeq * kB;       // 16384 GEMM rows
constexpr float kLog2e = 1.44269504088896340736f;

typedef __attribute__((ext_vector_type(8))) short bf16x8;
typedef __attribute__((ext_vector_type(4))) short bf16x4;
typedef __attribute__((ext_vector_type(4))) float f32x4;
typedef __attribute__((ext_vector_type(8))) unsigned short u16x8;
typedef __attribute__((ext_vector_type(4))) unsigned short u16x4;
typedef __attribute__((ext_vector_type(4))) unsigned u32x4;

#define AS1 __attribute__((address_space(1)))
#define AS3 __attribute__((address_space(3)))

__device__ __forceinline__ unsigned short f2bf(float x) {
  union { float f; unsigned u; } v; v.f = x;
  unsigned r = v.u + 0x7fffu + ((v.u >> 16) & 1u);   // RNE
  return (unsigned short)(r >> 16);
}
// HW packed f32->bf16 (RNE): D[15:0]=bf16(lo), D[31:16]=bf16(hi).
__device__ __forceinline__ unsigned cvtpk(float lo, float hi) {
  unsigned r;
  asm("v_cvt_pk_bf16_f32 %0, %1, %2" : "=v"(r) : "v"(lo), "v"(hi));
  return r;
}
// XOR swizzle for 128B-row-stride LDS tiles: xor byte bits 4-6 with row&7.
__device__ __forceinline__ int swz(int bo) { return bo ^ ((bo >> 3) & 0x70); }

__device__ __forceinline__ f32x4 mfma16x16(bf16x4 a, bf16x4 b, f32x4 c) {
#if __has_builtin(__builtin_amdgcn_mfma_f32_16x16x16bf16_1k)
  return __builtin_amdgcn_mfma_f32_16x16x16bf16_1k(a, b, c, 0, 0, 0);
#else
  asm volatile("v_mfma_f32_16x16x16_bf16 %0, %1, %2, %0\n\ts_nop 4"
               : "+v"(c) : "v"(a), "v"(b));
  return c;
#endif
}

// All four 1024x1024 weights -> bf16, dst contiguous (Wq|Wk|Wv|Wo).
__global__ __launch_bounds__(256) void cvt4(const float* __restrict__ s0,
                                            const float* __restrict__ s1,
                                            const float* __restrict__ s2,
                                            const float* __restrict__ s3,
                                            unsigned short* __restrict__ dst) {
  int i = blockIdx.x * 256 + threadIdx.x;          // 0 .. 4*2^18-1
  int t = i >> 18;
  int j = i & 0x3ffff;
  const float* s = (t == 0) ? s0 : (t == 1) ? s1 : (t == 2) ? s2 : s3;
  f32x4 v = *(const f32x4*)(s + (size_t)j * 4);
  u16x4 o;
  o[0] = f2bf(v[0]); o[1] = f2bf(v[1]); o[2] = f2bf(v[2]); o[3] = f2bf(v[3]);
  *(u16x4*)(dst + (size_t)i * 4) = o;
}

// ---- Fused QKV projection, 8-phase 256x256, 16 waves (64x64 per wave) ----
// 64 VGPR + 64 AGPR (acc) = 128/wave -> 4 waves/SIMD, no spill.
// LDS: A/B half-slots 128x64 bf16, slot(T,h)=(T&1)*2+h; chunk pos p of row r
// holds global chunk p^(r&7); ds_reads use sc=((kk*4+l4)^l7)*8.
// A = fp32 inputs, fused convert: p0/p1 load A(T+1) halves, p3 writes both
// (cvtpk + ds_write_b128). writeA's implicit reg-wait drains B(T+1) (FIFO);
// lgkmcnt(0) publishes the ds_writes before the phase-closing barrier.
__global__ __launch_bounds__(1024, 4) void gemm_qkv8(
    const float* __restrict__ qf, const float* __restrict__ kf,
    const float* __restrict__ vf, const unsigned short* __restrict__ Wcat,
    const float* __restrict__ bq, const float* __restrict__ bk,
    const float* __restrict__ bv, unsigned short* __restrict__ dst, float sQ) {
  constexpr int K = kDm, nkt = K / 64;   // 16
  __shared__ unsigned short sh[65536];   // 128 KB: A slots [0,32768), B [32768,65536)
  const int tid = (int)threadIdx.x;      // 0..1023
  const int l = tid & 63;
  const int l15 = l & 15, l4 = l >> 4, l7 = l15 & 7;
  const int wid = tid >> 6;              // 0..15
  const int wm = wid >> 2, wn = wid & 3;
  const int bid = (int)blockIdx.x;
  const int xcd = bid & 7, idx = bid >> 3;          // idx 0..95
  const int rbi = xcd * 8 + (idx & 7);              // 0..63
  const int cbi = idx >> 3;                         // 0..11
  const int mat = cbi >> 2, ccol = (cbi & 3) * 256;
  const float* bp = (mat == 0) ? bq : (mat == 1) ? bk : bv;
  const float scale = (mat == 0) ? sQ : 1.0f;
  const float* Ain = (mat == 0) ? qf : (mat == 1) ? kf : vf;
  unsigned short* out = dst + (size_t)mat * kMr * kDm;

  // A staging: thread owns row ar (0..127) of each half, 8 floats at chunk ac.
  const int ar = tid >> 3, ac = tid & 7;
  const float* gA = Ain + (size_t)(rbi * 256 + ar) * K + ac * 8;
  const int awp = (ac ^ (ar & 7)) * 8;              // write chunk pos (shorts)
  // B staging: 1 gload_lds chunk/thread/half; source pre-swizzled.
  const int srow = tid >> 3;
  const int g16 = (tid & 7) ^ (srow & 7);
  const unsigned short* gB = Wcat + (size_t)(cbi * 256 + srow) * K + g16 * 8;
  const int ldsbase = (tid & ~63) * 8;              // wave-uniform dest

  auto stageB = [&](int T, int h) {
    const unsigned short* s = gB + (size_t)h * (128 * K) + T * 64;
    unsigned short* d = sh + 32768 + ((T & 1) * 2 + h) * 8192 + ldsbase;
    __builtin_amdgcn_global_load_lds((const AS1 unsigned int*)s, (AS3 unsigned int*)d, 16, 0, 0);
  };
  auto loadA = [&](f32x4* r, int T, int h) {
    const float* s = gA + (size_t)h * (128 * K) + T * 64;
    r[0] = *(const f32x4*)s;
    r[1] = *(const f32x4*)(s + 4);
  };
  auto writeA = [&](const f32x4* r, int T, int h) {
    unsigned short* d = sh + ((T & 1) * 2 + h) * 8192 + ar * 64;
    u32x4 w = {cvtpk(r[0][0], r[0][1]), cvtpk(r[0][2], r[0][3]),
               cvtpk(r[1][0], r[1][1]), cvtpk(r[1][2], r[1][3])};
    *(u32x4*)(d + awp) = w;
  };

  f32x4 acc[4][4] = {};
  f32x4 a0[2], a1[2];        // 1-deep: A(T+1) halves (static-indexed)
  bf16x8 bfr[4];

  // Prologue: A(0) both halves -> regs; B(0),B(1) issued; write A(0);
  // implicit wait drains A(0); vmcnt(2) drains B(0), leaves B(1) in flight.
  loadA(a0, 0, 0); loadA(a1, 0, 1);
  stageB(0, 0); stageB(0, 1);
  stageB(1, 0); stageB(1, 1);
  writeA(a0, 0, 0); writeA(a1, 0, 1);
  asm volatile("s_waitcnt lgkmcnt(0)" ::: "memory");
  asm volatile("s_waitcnt vmcnt(2)" ::: "memory");
  __builtin_amdgcn_s_barrier();

  for (int it = 0; it < nkt / 2; ++it) {
#pragma unroll
    for (int tt = 0; tt < 2; ++tt) {
      const int T = 2 * it + tt;
      const unsigned short* Asl = sh + (tt * 2 + (wm >> 1)) * 8192;
      const unsigned short* Bsl = sh + 32768 + (tt * 2 + (wn >> 1)) * 8192;
      const int arow0 = (wm & 1) * 64;   // row base within 128-row half
      const int brow0 = (wn & 1) * 64;
#pragma unroll
      for (int p = 0; p < 4; ++p) {
        const int kk = p >> 1, mfh = p & 1;
        bf16x8 af[2];
        const int sc = ((kk * 4 + l4) ^ l7) * 8;
        if (mfh == 0) {
#pragma unroll
          for (int nf = 0; nf < 4; ++nf)
            bfr[nf] = *(const bf16x8*)&Bsl[(brow0 + nf * 16 + l15) * 64 + sc];
        }
#pragma unroll
        for (int i = 0; i < 2; ++i)
          af[i] = *(const bf16x8*)&Asl[(arow0 + mfh * 32 + i * 16 + l15) * 64 + sc];
        if (p == 0 && T + 1 < nkt) loadA(a0, T + 1, 0);
        if (p == 1 && T + 1 < nkt) loadA(a1, T + 1, 1);
        if (p == 3) {
          if (T + 2 < nkt) { stageB(T + 2, 0); stageB(T + 2, 1); }
          if (T + 1 < nkt) {   // implicit reg-wait here drains B(T+1) too
            writeA(a0, T + 1, 0);
            writeA(a1, T + 1, 1);
          }
        }
        __builtin_amdgcn_s_barrier();
        __builtin_amdgcn_s_setprio(1);
#pragma unroll
        for (int i = 0; i < 2; ++i)
#pragma unroll
          for (int nf = 0; nf < 4; ++nf)
            acc[mfh * 2 + i][nf] =
                __builtin_amdgcn_mfma_f32_16x16x32_bf16(af[i], bfr[nf], acc[mfh * 2 + i][nf], 0, 0, 0);
        __builtin_amdgcn_s_setprio(0);
        if (p == 3) {
          asm volatile("s_waitcnt lgkmcnt(0)" ::: "memory");  // publish A writes
          if (T + 1 == nkt - 1)   // tail: drain last B before its tile
            asm volatile("s_waitcnt vmcnt(0)" ::: "memory");
        }
        __builtin_amdgcn_s_barrier();
      }
    }
  }

  // Epilogue: restage 256x256 C into LDS (store-order + XOR swz), then
  // coalesced head-major stores (1024 threads, 16 groups).
#pragma unroll
  for (int mf = 0; mf < 4; ++mf)
#pragma unroll
    for (int nf = 0; nf < 4; ++nf) {
      int col = wn * 64 + nf * 16 + l15;            // tile-local col 0..255
      float bvv = bp[ccol + col];
      int grpc = col >> 6;
      int c16 = (col & 63) >> 3, pos = col & 7;
      unsigned p01 = cvtpk((acc[mf][nf][0] + bvv) * scale, (acc[mf][nf][1] + bvv) * scale);
      unsigned p23 = cvtpk((acc[mf][nf][2] + bvv) * scale, (acc[mf][nf][3] + bvv) * scale);
      unsigned short ev[4] = {(unsigned short)p01, (unsigned short)(p01 >> 16),
                              (unsigned short)p23, (unsigned short)(p23 >> 16)};
#pragma unroll
      for (int j = 0; j < 4; ++j) {
        int tl = wm * 64 + mf * 16 + l4 * 4 + j;    // tile-local row 0..255
        int grp = (tl & 3) * 4 + grpc;
        int u = (tl >> 2) * 8 + c16;
        int byte = (grp * 8192 + u * 16 + pos * 2) ^ (((u >> 3) & 7) << 4);
        *(unsigned short*)((char*)sh + byte) = ev[j];
      }
    }
  __syncthreads();
  {
    int inner = tid & 63, grp = tid >> 6;           // grp = b2*4 + hl (16 groups)
    int b2 = grp >> 2, hl = grp & 3;
    int h = (cbi & 3) * 4 + hl;
    unsigned short* po = out + ((size_t)(b2 * kNh + h) * kSeq + rbi * 64) * kDk;
#pragma unroll
    for (int i = 0; i < 8; ++i) {
      int u = i * 64 + inner;
      int byte = (grp * 8192 + u * 16) ^ (((u >> 3) & 7) << 4);
      u16x8 v = *(const u16x8*)((const char*)sh + byte);
      *(u16x8*)(po + u * 8) = v;
    }
  }
}

// ---- Output projection, 8-phase 256x256, 16 waves (64x64 per wave) ----
// A = head-major bf16 via gload_lds (1 chunk/thread/half, source pre-swz);
// K-tile T == head T -> uniform source offset T*kSeq*kDk. No fp32 A-state
// -> ~64 VGPR + 64 AGPR, 4 waves/SIMD. Gates: p3 vmcnt(2) drains
// B(T+1)+A(T+1), leaves B(T+2); tail vmcnt(0).
__global__ __launch_bounds__(1024, 4) void gemm_o8(const unsigned short* __restrict__ Aw,
                                                   const unsigned short* __restrict__ Bw,
                                                   const float* __restrict__ bias,
                                                   float* __restrict__ Cp) {
  constexpr int K = kDm, nkt = K / 64;   // 16
  __shared__ unsigned short sh[65536];
  const int tid = (int)threadIdx.x;
  const int l = tid & 63;
  const int l15 = l & 15, l4 = l >> 4, l7 = l15 & 7;
  const int wid = tid >> 6;
  const int wm = wid >> 2, wn = wid & 3;
  const int bid = (int)blockIdx.x;
  const int xcd = bid & 7, idx = bid >> 3;          // idx 0..31
  const int rbi = xcd * 8 + (idx & 7);              // 0..63
  const int cbi = idx >> 3;                         // 0..3
  const int rb = rbi * 256, cb = cbi * 256;

  const int srow = tid >> 3;                        // 0..127
  const int g16 = (tid & 7) ^ (srow & 7);
  size_t abase[2];
#pragma unroll
  for (int h = 0; h < 2; ++h) {
    int t = rb + h * 128 + srow;
    abase[h] = ((size_t)((t & 3) * kNh) * kSeq + (t >> 2)) * kDk + g16 * 8;
  }
  const unsigned short* gB = Bw + (size_t)(cb + srow) * K + g16 * 8;
  const int ldsbase = (tid & ~63) * 8;

  auto stageA = [&](int T, int h) {
    unsigned short* d = sh + ((T & 1) * 2 + h) * 8192 + ldsbase;
    size_t ko = (size_t)T * ((size_t)kSeq * kDk);   // head T
    __builtin_amdgcn_global_load_lds((const AS1 unsigned int*)(Aw + abase[h] + ko),
                                     (AS3 unsigned int*)d, 16, 0, 0);
  };
  auto stageB = [&](int T, int h) {
    const unsigned short* s = gB + (size_t)h * (128 * K) + T * 64;
    unsigned short* d = sh + 32768 + ((T & 1) * 2 + h) * 8192 + ldsbase;
    __builtin_amdgcn_global_load_lds((const AS1 unsigned int*)s, (AS3 unsigned int*)d, 16, 0, 0);
  };

  f32x4 acc[4][4] = {};
  bf16x8 bfr[4];

  stageB(0, 0); stageB(0, 1);
  stageA(0, 0); stageA(0, 1);
  stageB(1, 0); stageB(1, 1);
  asm volatile("s_waitcnt vmcnt(2)" ::: "memory");
  __builtin_amdgcn_s_barrier();

  for (int it = 0; it < nkt / 2; ++it) {
#pragma unroll
    for (int tt = 0; tt < 2; ++tt) {
      const int T = 2 * it + tt;
      const unsigned short* Asl = sh + (tt * 2 + (wm >> 1)) * 8192;
      const unsigned short* Bsl = sh + 32768 + (tt * 2 + (wn >> 1)) * 8192;
      const int arow0 = (wm & 1) * 64;
      const int brow0 = (wn & 1) * 64;
#pragma unroll
      for (int p = 0; p < 4; ++p) {
        const int kk = p >> 1, mfh = p & 1;
        bf16x8 af[2];
        const int sc = ((kk * 4 + l4) ^ l7) * 8;
        if (mfh == 0) {
#pragma unroll
          for (int nf = 0; nf < 4; ++nf)
            bfr[nf] = *(const bf16x8*)&Bsl[(brow0 + nf * 16 + l15) * 64 + sc];
        }
#pragma unroll
        for (int i = 0; i < 2; ++i)
          af[i] = *(const bf16x8*)&Asl[(arow0 + mfh * 32 + i * 16 + l15) * 64 + sc];
        if (p == 0 && T + 1 < nkt) stageA(T + 1, 0);
        if (p == 1 && T + 1 < nkt) stageA(T + 1, 1);
        if (p == 3 && T + 2 < nkt) { stageB(T + 2, 0); stageB(T + 2, 1); }
        __builtin_amdgcn_s_barrier();
        __builtin_amdgcn_s_setprio(1);
#pragma unroll
        for (int i = 0; i < 2; ++i)
#pragma unroll
          for (int nf = 0; nf < 4; ++nf)
            acc[mfh * 2 + i][nf] =
                __builtin_amdgcn_mfma_f32_16x16x32_bf16(af[i], bfr[nf], acc[mfh * 2 + i][nf], 0, 0, 0);
        __builtin_amdgcn_s_setprio(0);
        if (p == 3 && T + 1 < nkt) {   // drain B(T+1)+A(T+1); B(T+2) in flight
          if (T + 2 < nkt) asm volatile("s_waitcnt vmcnt(2)" ::: "memory");
          else             asm volatile("s_waitcnt vmcnt(0)" ::: "memory");
        }
        __builtin_amdgcn_s_barrier();
      }
    }
  }

  // Direct fp32 epilogue.
#pragma unroll
  for (int nf = 0; nf < 4; ++nf) {
    int col = cb + wn * 64 + nf * 16 + l15;
    float bvv = bias[col];
#pragma unroll
    for (int mf = 0; mf < 4; ++mf) {
      int row0 = rb + wm * 64 + mf * 16 + l4 * 4;
#pragma unroll
      for (int j = 0; j < 4; ++j)
        Cp[(size_t)(row0 + j) * kDm + col] = acc[mf][nf][j] + bvv;
    }
  }
}

// Block-diagonal flash attention, head-major (B*H, S, dk) in/out.
__global__ __launch_bounds__(256) void attn_blkdiag(const unsigned short* __restrict__ qw,
                                                    const unsigned short* __restrict__ kw,
                                                    const unsigned short* __restrict__ vw,
                                                    unsigned short* __restrict__ ow) {
  __shared__ unsigned short Kl[64 * 64];       // [kv_row][d]   (swizzled)
  __shared__ unsigned short Vt[64 * 64];       // [d][kv_row]   (transposed, swizzled)
  const int tid = (int)threadIdx.x;
  const int w = tid >> 6, l = tid & 63;
  const int l15 = l & 15, l4 = l >> 4;
  const int bid0 = (int)blockIdx.x;
  const int bid = (bid0 & 7) * 256 + (bid0 >> 3);   // XCD swizzle, 2048 % 8 == 0
  const int hf = bid & 1, c = (bid >> 1) & 15, bh = bid >> 5;
  const size_t base = ((size_t)bh * kSeq + c * kChk) * kDk;
  const unsigned short* qp = qw + base + (size_t)hf * 128 * kDk;
  const unsigned short* kp = kw + base;
  const unsigned short* vp = vw + base;

  bf16x8 q[2][2];
#pragma unroll
  for (int m = 0; m < 2; ++m)
#pragma unroll
    for (int kk = 0; kk < 2; ++kk)
      q[m][kk] = *(const bf16x8*)(qp + (w * 32 + m * 16 + l15) * 64 + kk * 32 + l4 * 8);

  float mst[2] = {-1e30f, -1e30f}, lst[2] = {0.f, 0.f};
  f32x4 oacc[2][4] = {};

  const int r = tid >> 2, c0 = (tid & 3) * 16;
  u16x8 kr0, kr1, vr0, vr1;
  {
    const unsigned short* kt = kp + tid * 16;
    kr0 = *(const u16x8*)kt; kr1 = *(const u16x8*)(kt + 8);
    const unsigned short* vt = vp + tid * 16;
    vr0 = *(const u16x8*)vt; vr1 = *(const u16x8*)(vt + 8);
  }

  for (int kb = 0; kb < 4; ++kb) {
    __syncthreads();
    {
      int bo = r * 128 + c0 * 2;
      *(u16x8*)((char*)Kl + swz(bo)) = kr0;
      *(u16x8*)((char*)Kl + swz(bo + 16)) = kr1;
#pragma unroll
      for (int j = 0; j < 8; ++j) {
        *(unsigned short*)((char*)Vt + swz((c0 + j) * 128 + r * 2)) = vr0[j];
        *(unsigned short*)((char*)Vt + swz((c0 + 8 + j) * 128 + r * 2)) = vr1[j];
      }
    }
    __syncthreads();
    if (kb < 3) {
      const unsigned short* kt = kp + (kb + 1) * (64 * kDk) + tid * 16;
      kr0 = *(const u16x8*)kt; kr1 = *(const u16x8*)(kt + 8);
      const unsigned short* vt = vp + (kb + 1) * (64 * kDk) + tid * 16;
      vr0 = *(const u16x8*)vt; vr1 = *(const u16x8*)(vt + 8);
    }

    f32x4 sacc[4][2] = {};
    __builtin_amdgcn_s_setprio(1);
#pragma unroll
    for (int kk = 0; kk < 2; ++kk) {
      bf16x8 kf[4];
#pragma unroll
      for (int kn = 0; kn < 4; ++kn) {
        int bo = (kn * 16 + l15) * 128 + (kk * 32 + l4 * 8) * 2;
        kf[kn] = *(const bf16x8*)((const char*)Kl + swz(bo));
      }
#pragma unroll
      for (int kn = 0; kn < 4; ++kn)
#pragma unroll
        for (int m = 0; m < 2; ++m)
          sacc[kn][m] = __builtin_amdgcn_mfma_f32_16x16x32_bf16(kf[kn], q[m][kk], sacc[kn][m], 0, 0, 0);
    }
    __builtin_amdgcn_s_setprio(0);

    unsigned pw[2][4][2];
    float cbq[2][4];
#pragma unroll
    for (int m = 0; m < 2; ++m) {
      float rm = -1e30f;
#pragma unroll
      for (int kn = 0; kn < 4; ++kn)
#pragma unroll
        for (int j = 0; j < 4; ++j) rm = fmaxf(rm, sacc[kn][m][j]);
      rm = fmaxf(rm, __shfl_xor(rm, 16, 64));
      rm = fmaxf(rm, __shfl_xor(rm, 32, 64));
      float mn = fmaxf(mst[m], rm);
      float corr = exp2f(mst[m] - mn);
      mst[m] = mn;
      float rs = 0.f;
#pragma unroll
      for (int kn = 0; kn < 4; ++kn) {
#pragma unroll
        for (int j = 0; j < 4; ++j) {
          float p = exp2f(sacc[kn][m][j] - mn);
          sacc[kn][m][j] = p;
          rs += p;
        }
        pw[m][kn][0] = cvtpk(sacc[kn][m][0], sacc[kn][m][1]);
        pw[m][kn][1] = cvtpk(sacc[kn][m][2], sacc[kn][m][3]);
      }
      rs += __shfl_xor(rs, 16, 64);
      rs += __shfl_xor(rs, 32, 64);
      lst[m] = lst[m] * corr + rs;
#pragma unroll
      for (int j = 0; j < 4; ++j) cbq[m][j] = __shfl(corr, l4 * 4 + j, 64);
#pragma unroll
      for (int n = 0; n < 4; ++n)
#pragma unroll
        for (int j = 0; j < 4; ++j) oacc[m][n][j] *= cbq[m][j];
    }

    __builtin_amdgcn_s_setprio(1);
#pragma unroll
    for (int kn = 0; kn < 4; ++kn) {
      bf16x4 vf[4];
#pragma unroll
      for (int n = 0; n < 4; ++n) {
        int bo = (n * 16 + l15) * 128 + (kn * 16 + l4 * 4) * 2;
        vf[n] = *(const bf16x4*)((const char*)Vt + swz(bo));
      }
#pragma unroll
      for (int m = 0; m < 2; ++m) {
        union { unsigned u[2]; bf16x4 h; } pk;
        pk.u[0] = pw[m][kn][0]; pk.u[1] = pw[m][kn][1];
#pragma unroll
        for (int n = 0; n < 4; ++n)
          oacc[m][n] = mfma16x16(pk.h, vf[n], oacc[m][n]);
      }
    }
    __builtin_amdgcn_s_setprio(0);
  }

  unsigned short* op = ow + base + (size_t)hf * 128 * kDk;
#pragma unroll
  for (int m = 0; m < 2; ++m) {
    float inv = 1.f / lst[m];
#pragma unroll
    for (int j = 0; j < 4; ++j) {
      float ib = __shfl(inv, l4 * 4 + j, 64);
      int srow = w * 32 + m * 16 + l4 * 4 + j;
#pragma unroll
      for (int n = 0; n < 4; ++n)
        op[(size_t)srow * 64 + n * 16 + l15] = f2bf(oacc[m][n][j] * ib);
    }
  }
}

}  // namespace

extern "C" void kernel_launch(void* const* d_in, const int* in_sizes, int n_in,
                              void* d_out, int out_size, void* d_ws, size_t ws_size,
                              hipStream_t stream) {
  const float* query = (const float*)d_in[0];
  const float* key   = (const float*)d_in[1];
  const float* value = (const float*)d_in[2];
  const float* Wq = (const float*)d_in[3];
  const float* bq = (const float*)d_in[4];
  const float* Wk = (const float*)d_in[5];
  const float* bk = (const float*)d_in[6];
  const float* Wv = (const float*)d_in[7];
  const float* bv = (const float*)d_in[8];
  const float* Wo = (const float*)d_in[9];
  const float* bo = (const float*)d_in[10];

  const float sQ = 0.125f * kLog2e;   // 1/sqrt(dk) * log2(e), folded into Q proj

  const size_t wsz = (size_t)kDm * kDm;          // 1M elems
  const size_t tsz = (size_t)kMr * kDm;          // 16M elems
  unsigned short* wsp = (unsigned short*)d_ws;
  unsigned short* wqb = wsp;                     // Wq|Wk|Wv|Wo contiguous
  unsigned short* wob = wqb + 3 * wsz;
  unsigned short* qws = wqb + 4 * wsz;
  unsigned short* kws = qws + tsz;
  unsigned short* vws = kws + tsz;
  unsigned short* aws = vws + tsz;

  const size_t need = (4 * wsz + 4 * tsz) * 2;   // 136 MB
  if (ws_size < need) return;

  cvt4<<<dim3(4096), dim3(256), 0, stream>>>(Wq, Wk, Wv, Wo, wqb);
  gemm_qkv8<<<dim3(768), dim3(1024), 0, stream>>>(query, key, value, wqb,
                                                  bq, bk, bv, qws, sQ);
  attn_blkdiag<<<dim3(2048), 256, 0, stream>>>(qws, kws, vws, aws);
  gemm_o8<<<dim3(256), dim3(1024), 0, stream>>>(aws, wob, bo, (float*)d_out);
}

// Round 20
// 241.688 us; speedup vs baseline: 1.0104x; 1.0104x over previous
//
#include <hip/hip_runtime.h>
#include <hip/hip_bf16.h>

// MemoryEfficientMultiheadAttention: chunked (block-diagonal) MHA.
// S=4096, B=4, D=1024, H=16, dk=64, CHUNK=256.
// FINAL (session best, 242.1 us; 2.08x vs first correct kernel):
// cvt(weights) -> fused QKV GEMM (8-phase 256x256, 16 waves x 64x64/wave,
// 4 waves/SIMD, fused fp32->bf16 A staging, 1-deep A pipeline)
// -> flash attn (swapped QK^T, P-in-reg PV) -> out proj (8-wave 8-phase).

namespace {

constexpr int kSeq = 4096, kB = 4, kDm = 1024, kNh = 16, kDk = 64, kChk = 256;
constexpr int kMr = kSeq * kB;       // 16384 GEMM rows
constexpr float kLog2e = 1.44269504088896340736f;

typedef __attribute__((ext_vector_type(8))) short bf16x8;
typedef __attribute__((ext_vector_type(4))) short bf16x4;
typedef __attribute__((ext_vector_type(4))) float f32x4;
typedef __attribute__((ext_vector_type(8))) unsigned short u16x8;
typedef __attribute__((ext_vector_type(4))) unsigned short u16x4;
typedef __attribute__((ext_vector_type(4))) unsigned u32x4;

#define AS1 __attribute__((address_space(1)))
#define AS3 __attribute__((address_space(3)))

__device__ __forceinline__ unsigned short f2bf(float x) {
  union { float f; unsigned u; } v; v.f = x;
  unsigned r = v.u + 0x7fffu + ((v.u >> 16) & 1u);   // RNE
  return (unsigned short)(r >> 16);
}
// HW packed f32->bf16 (RNE): D[15:0]=bf16(lo), D[31:16]=bf16(hi).
__device__ __forceinline__ unsigned cvtpk(float lo, float hi) {
  unsigned r;
  asm("v_cvt_pk_bf16_f32 %0, %1, %2" : "=v"(r) : "v"(lo), "v"(hi));
  return r;
}
// XOR swizzle for 128B-row-stride LDS tiles: xor byte bits 4-6 with row&7.
__device__ __forceinline__ int swz(int bo) { return bo ^ ((bo >> 3) & 0x70); }

__device__ __forceinline__ f32x4 mfma16x16(bf16x4 a, bf16x4 b, f32x4 c) {
#if __has_builtin(__builtin_amdgcn_mfma_f32_16x16x16bf16_1k)
  return __builtin_amdgcn_mfma_f32_16x16x16bf16_1k(a, b, c, 0, 0, 0);
#else
  asm volatile("v_mfma_f32_16x16x16_bf16 %0, %1, %2, %0\n\ts_nop 4"
               : "+v"(c) : "v"(a), "v"(b));
  return c;
#endif
}

// All four 1024x1024 weights -> bf16, dst contiguous (Wq|Wk|Wv|Wo).
__global__ __launch_bounds__(256) void cvt4(const float* __restrict__ s0,
                                            const float* __restrict__ s1,
                                            const float* __restrict__ s2,
                                            const float* __restrict__ s3,
                                            unsigned short* __restrict__ dst) {
  int i = blockIdx.x * 256 + threadIdx.x;          // 0 .. 4*2^18-1
  int t = i >> 18;
  int j = i & 0x3ffff;
  const float* s = (t == 0) ? s0 : (t == 1) ? s1 : (t == 2) ? s2 : s3;
  f32x4 v = *(const f32x4*)(s + (size_t)j * 4);
  u16x4 o;
  o[0] = f2bf(v[0]); o[1] = f2bf(v[1]); o[2] = f2bf(v[2]); o[3] = f2bf(v[3]);
  *(u16x4*)(dst + (size_t)i * 4) = o;
}

// ---- Fused QKV projection, 8-phase 256x256, 16 waves (64x64 per wave) ----
// 64 VGPR + 64 AGPR (acc) = 128/wave -> 4 waves/SIMD, no spill.
// LDS: A/B half-slots 128x64 bf16, slot(T,h)=(T&1)*2+h; chunk pos p of row r
// holds global chunk p^(r&7); ds_reads use sc=((kk*4+l4)^l7)*8.
// A = fp32 inputs, fused convert: p0/p1 load A(T+1) halves, p3 writes both
// (cvtpk + ds_write_b128). writeA's implicit reg-wait drains B(T+1) (FIFO);
// lgkmcnt(0) publishes the ds_writes before the phase-closing barrier.
__global__ __launch_bounds__(1024, 4) void gemm_qkv8(
    const float* __restrict__ qf, const float* __restrict__ kf,
    const float* __restrict__ vf, const unsigned short* __restrict__ Wcat,
    const float* __restrict__ bq, const float* __restrict__ bk,
    const float* __restrict__ bv, unsigned short* __restrict__ dst, float sQ) {
  constexpr int K = kDm, nkt = K / 64;   // 16
  __shared__ unsigned short sh[65536];   // 128 KB: A slots [0,32768), B [32768,65536)
  const int tid = (int)threadIdx.x;      // 0..1023
  const int l = tid & 63;
  const int l15 = l & 15, l4 = l >> 4, l7 = l15 & 7;
  const int wid = tid >> 6;              // 0..15
  const int wm = wid >> 2, wn = wid & 3;
  const int bid = (int)blockIdx.x;
  const int xcd = bid & 7, idx = bid >> 3;          // idx 0..95
  const int rbi = xcd * 8 + (idx & 7);              // 0..63
  const int cbi = idx >> 3;                         // 0..11
  const int mat = cbi >> 2, ccol = (cbi & 3) * 256;
  const float* bp = (mat == 0) ? bq : (mat == 1) ? bk : bv;
  const float scale = (mat == 0) ? sQ : 1.0f;
  const float* Ain = (mat == 0) ? qf : (mat == 1) ? kf : vf;
  unsigned short* out = dst + (size_t)mat * kMr * kDm;

  // A staging: thread owns row ar (0..127) of each half, 8 floats at chunk ac.
  const int ar = tid >> 3, ac = tid & 7;
  const float* gA = Ain + (size_t)(rbi * 256 + ar) * K + ac * 8;
  const int awp = (ac ^ (ar & 7)) * 8;              // write chunk pos (shorts)
  // B staging: 1 gload_lds chunk/thread/half; source pre-swizzled.
  const int srow = tid >> 3;
  const int g16 = (tid & 7) ^ (srow & 7);
  const unsigned short* gB = Wcat + (size_t)(cbi * 256 + srow) * K + g16 * 8;
  const int ldsbase = (tid & ~63) * 8;              // wave-uniform dest

  auto stageB = [&](int T, int h) {
    const unsigned short* s = gB + (size_t)h * (128 * K) + T * 64;
    unsigned short* d = sh + 32768 + ((T & 1) * 2 + h) * 8192 + ldsbase;
    __builtin_amdgcn_global_load_lds((const AS1 unsigned int*)s, (AS3 unsigned int*)d, 16, 0, 0);
  };
  auto loadA = [&](f32x4* r, int T, int h) {
    const float* s = gA + (size_t)h * (128 * K) + T * 64;
    r[0] = *(const f32x4*)s;
    r[1] = *(const f32x4*)(s + 4);
  };
  auto writeA = [&](const f32x4* r, int T, int h) {
    unsigned short* d = sh + ((T & 1) * 2 + h) * 8192 + ar * 64;
    u32x4 w = {cvtpk(r[0][0], r[0][1]), cvtpk(r[0][2], r[0][3]),
               cvtpk(r[1][0], r[1][1]), cvtpk(r[1][2], r[1][3])};
    *(u32x4*)(d + awp) = w;
  };

  f32x4 acc[4][4] = {};
  f32x4 a0[2], a1[2];        // 1-deep: A(T+1) halves (static-indexed)
  bf16x8 bfr[4];

  // Prologue: A(0) both halves -> regs; B(0),B(1) issued; write A(0);
  // implicit wait drains A(0); vmcnt(2) drains B(0), leaves B(1) in flight.
  loadA(a0, 0, 0); loadA(a1, 0, 1);
  stageB(0, 0); stageB(0, 1);
  stageB(1, 0); stageB(1, 1);
  writeA(a0, 0, 0); writeA(a1, 0, 1);
  asm volatile("s_waitcnt lgkmcnt(0)" ::: "memory");
  asm volatile("s_waitcnt vmcnt(2)" ::: "memory");
  __builtin_amdgcn_s_barrier();

  for (int it = 0; it < nkt / 2; ++it) {
#pragma unroll
    for (int tt = 0; tt < 2; ++tt) {
      const int T = 2 * it + tt;
      const unsigned short* Asl = sh + (tt * 2 + (wm >> 1)) * 8192;
      const unsigned short* Bsl = sh + 32768 + (tt * 2 + (wn >> 1)) * 8192;
      const int arow0 = (wm & 1) * 64;   // row base within 128-row half
      const int brow0 = (wn & 1) * 64;
#pragma unroll
      for (int p = 0; p < 4; ++p) {
        const int kk = p >> 1, mfh = p & 1;
        bf16x8 af[2];
        const int sc = ((kk * 4 + l4) ^ l7) * 8;
        if (mfh == 0) {
#pragma unroll
          for (int nf = 0; nf < 4; ++nf)
            bfr[nf] = *(const bf16x8*)&Bsl[(brow0 + nf * 16 + l15) * 64 + sc];
        }
#pragma unroll
        for (int i = 0; i < 2; ++i)
          af[i] = *(const bf16x8*)&Asl[(arow0 + mfh * 32 + i * 16 + l15) * 64 + sc];
        if (p == 0 && T + 1 < nkt) loadA(a0, T + 1, 0);
        if (p == 1 && T + 1 < nkt) loadA(a1, T + 1, 1);
        if (p == 3) {
          if (T + 2 < nkt) { stageB(T + 2, 0); stageB(T + 2, 1); }
          if (T + 1 < nkt) {   // implicit reg-wait here drains B(T+1) too
            writeA(a0, T + 1, 0);
            writeA(a1, T + 1, 1);
          }
        }
        __builtin_amdgcn_s_barrier();
        __builtin_amdgcn_s_setprio(1);
#pragma unroll
        for (int i = 0; i < 2; ++i)
#pragma unroll
          for (int nf = 0; nf < 4; ++nf)
            acc[mfh * 2 + i][nf] =
                __builtin_amdgcn_mfma_f32_16x16x32_bf16(af[i], bfr[nf], acc[mfh * 2 + i][nf], 0, 0, 0);
        __builtin_amdgcn_s_setprio(0);
        if (p == 3) {
          asm volatile("s_waitcnt lgkmcnt(0)" ::: "memory");  // publish A writes
          if (T + 1 == nkt - 1)   // tail: drain last B before its tile
            asm volatile("s_waitcnt vmcnt(0)" ::: "memory");
        }
        __builtin_amdgcn_s_barrier();
      }
    }
  }

  // Epilogue: restage 256x256 C into LDS (store-order + XOR swz), then
  // coalesced head-major stores (1024 threads, 16 groups).
#pragma unroll
  for (int mf = 0; mf < 4; ++mf)
#pragma unroll
    for (int nf = 0; nf < 4; ++nf) {
      int col = wn * 64 + nf * 16 + l15;            // tile-local col 0..255
      float bvv = bp[ccol + col];
      int grpc = col >> 6;
      int c16 = (col & 63) >> 3, pos = col & 7;
      unsigned p01 = cvtpk((acc[mf][nf][0] + bvv) * scale, (acc[mf][nf][1] + bvv) * scale);
      unsigned p23 = cvtpk((acc[mf][nf][2] + bvv) * scale, (acc[mf][nf][3] + bvv) * scale);
      unsigned short ev[4] = {(unsigned short)p01, (unsigned short)(p01 >> 16),
                              (unsigned short)p23, (unsigned short)(p23 >> 16)};
#pragma unroll
      for (int j = 0; j < 4; ++j) {
        int tl = wm * 64 + mf * 16 + l4 * 4 + j;    // tile-local row 0..255
        int grp = (tl & 3) * 4 + grpc;
        int u = (tl >> 2) * 8 + c16;
        int byte = (grp * 8192 + u * 16 + pos * 2) ^ (((u >> 3) & 7) << 4);
        *(unsigned short*)((char*)sh + byte) = ev[j];
      }
    }
  __syncthreads();
  {
    int inner = tid & 63, grp = tid >> 6;           // grp = b2*4 + hl (16 groups)
    int b2 = grp >> 2, hl = grp & 3;
    int h = (cbi & 3) * 4 + hl;
    unsigned short* po = out + ((size_t)(b2 * kNh + h) * kSeq + rbi * 64) * kDk;
#pragma unroll
    for (int i = 0; i < 8; ++i) {
      int u = i * 64 + inner;
      int byte = (grp * 8192 + u * 16) ^ (((u >> 3) & 7) << 4);
      u16x8 v = *(const u16x8*)((const char*)sh + byte);
      *(u16x8*)(po + u * 8) = v;
    }
  }
}

// ---- Output projection, 8-phase 256x256 template (8 waves, proven) ----
__global__ __launch_bounds__(512, 2) void gemm_o8(const unsigned short* __restrict__ Aw,
                                                  const unsigned short* __restrict__ Bw,
                                                  const float* __restrict__ bias,
                                                  float* __restrict__ Cp) {
  constexpr int K = kDm, nkt = K / 64;   // 16
  __shared__ unsigned short sh[65536];
  const int tid = (int)threadIdx.x;
  const int l = tid & 63;
  const int l15 = l & 15, l4 = l >> 4, l7 = l15 & 7;
  const int wid = tid >> 6, wm = wid >> 2, wn = wid & 3, wn1 = wn & 1;
  const int bid = (int)blockIdx.x;
  const int xcd = bid & 7, idx = bid >> 3;          // idx 0..31
  const int rbi = xcd * 8 + (idx & 7);              // 0..63
  const int cbi = idx >> 3;                         // 0..3
  const int rb = rbi * 256, cb = cbi * 256;

  const int srow = tid >> 3;
  const int g16 = (tid & 7) ^ (srow & 7);
  size_t abase[2][2];
#pragma unroll
  for (int h = 0; h < 2; ++h)
#pragma unroll
    for (int i = 0; i < 2; ++i) {
      int t = rb + h * 128 + srow + 64 * i;
      abase[h][i] = ((size_t)((t & 3) * kNh) * kSeq + (t >> 2)) * kDk + g16 * 8;
    }
  const unsigned short* gB = Bw + (size_t)(cb + srow) * K + g16 * 8;
  const int ldsbase = (tid & ~63) * 8;

  auto stageA = [&](int T, int h) {
    unsigned short* d = sh + ((T & 1) * 2 + h) * 8192 + ldsbase;
    size_t ko = (size_t)T * ((size_t)kSeq * kDk);   // head T
    __builtin_amdgcn_global_load_lds((const AS1 unsigned int*)(Aw + abase[h][0] + ko),
                                     (AS3 unsigned int*)d, 16, 0, 0);
    __builtin_amdgcn_global_load_lds((const AS1 unsigned int*)(Aw + abase[h][1] + ko),
                                     (AS3 unsigned int*)(d + 4096), 16, 0, 0);
  };
  auto stageB = [&](int T, int h) {
    const unsigned short* s = gB + (size_t)h * (128 * K) + T * 64;
    unsigned short* d = sh + 32768 + ((T & 1) * 2 + h) * 8192 + ldsbase;
    __builtin_amdgcn_global_load_lds((const AS1 unsigned int*)s, (AS3 unsigned int*)d, 16, 0, 0);
    __builtin_amdgcn_global_load_lds((const AS1 unsigned int*)(s + 64 * K),
                                     (AS3 unsigned int*)(d + 4096), 16, 0, 0);
  };

  f32x4 acc[8][4] = {};
  bf16x8 bfr[4];

  stageB(0, 0); stageB(0, 1);
  stageA(0, 0); stageA(0, 1);
  stageB(1, 0); stageB(1, 1);
  asm volatile("s_waitcnt vmcnt(4)" ::: "memory");
  __builtin_amdgcn_s_barrier();

  for (int it = 0; it < nkt / 2; ++it) {
#pragma unroll
    for (int tt = 0; tt < 2; ++tt) {
      const int T = 2 * it + tt;
      const unsigned short* Asl = sh + (tt * 2 + wm) * 8192;
      const unsigned short* Bsl = sh + 32768 + (tt * 2 + (wn >> 1)) * 8192;
#pragma unroll
      for (int p = 0; p < 4; ++p) {
        const int kk = p >> 1, mfh = p & 1;
        bf16x8 af[4];
        const int sc = ((kk * 4 + l4) ^ l7) * 8;
        if (mfh == 0) {
#pragma unroll
          for (int nf = 0; nf < 4; ++nf)
            bfr[nf] = *(const bf16x8*)&Bsl[(wn1 * 64 + nf * 16 + l15) * 64 + sc];
        }
#pragma unroll
        for (int i = 0; i < 4; ++i)
          af[i] = *(const bf16x8*)&Asl[(mfh * 64 + i * 16 + l15) * 64 + sc];
        if (p == 0 && T + 1 < nkt) stageA(T + 1, 0);
        if (p == 1 && T + 1 < nkt) stageA(T + 1, 1);
        if (p == 3 && T + 2 < nkt) { stageB(T + 2, 0); stageB(T + 2, 1); }
        __builtin_amdgcn_s_barrier();
        __builtin_amdgcn_s_setprio(1);
#pragma unroll
        for (int i = 0; i < 4; ++i)
#pragma unroll
          for (int nf = 0; nf < 4; ++nf)
            acc[mfh * 4 + i][nf] =
                __builtin_amdgcn_mfma_f32_16x16x32_bf16(af[i], bfr[nf], acc[mfh * 4 + i][nf], 0, 0, 0);
        __builtin_amdgcn_s_setprio(0);
        if (p == 3 && T + 1 < nkt) {
          if (T + 2 < nkt) asm volatile("s_waitcnt vmcnt(4)" ::: "memory");
          else             asm volatile("s_waitcnt vmcnt(0)" ::: "memory");
        }
        __builtin_amdgcn_s_barrier();
      }
    }
  }

#pragma unroll
  for (int nf = 0; nf < 4; ++nf) {
    int col = cb + wn * 64 + nf * 16 + l15;
    float bvv = bias[col];
#pragma unroll
    for (int mf = 0; mf < 8; ++mf) {
      int row0 = rb + wm * 128 + mf * 16 + l4 * 4;
#pragma unroll
      for (int j = 0; j < 4; ++j)
        Cp[(size_t)(row0 + j) * kDm + col] = acc[mf][nf][j] + bvv;
    }
  }
}

// Block-diagonal flash attention, head-major (B*H, S, dk) in/out.
__global__ __launch_bounds__(256) void attn_blkdiag(const unsigned short* __restrict__ qw,
                                                    const unsigned short* __restrict__ kw,
                                                    const unsigned short* __restrict__ vw,
                                                    unsigned short* __restrict__ ow) {
  __shared__ unsigned short Kl[64 * 64];       // [kv_row][d]   (swizzled)
  __shared__ unsigned short Vt[64 * 64];       // [d][kv_row]   (transposed, swizzled)
  const int tid = (int)threadIdx.x;
  const int w = tid >> 6, l = tid & 63;
  const int l15 = l & 15, l4 = l >> 4;
  const int bid0 = (int)blockIdx.x;
  const int bid = (bid0 & 7) * 256 + (bid0 >> 3);   // XCD swizzle, 2048 % 8 == 0
  const int hf = bid & 1, c = (bid >> 1) & 15, bh = bid >> 5;
  const size_t base = ((size_t)bh * kSeq + c * kChk) * kDk;
  const unsigned short* qp = qw + base + (size_t)hf * 128 * kDk;
  const unsigned short* kp = kw + base;
  const unsigned short* vp = vw + base;

  bf16x8 q[2][2];
#pragma unroll
  for (int m = 0; m < 2; ++m)
#pragma unroll
    for (int kk = 0; kk < 2; ++kk)
      q[m][kk] = *(const bf16x8*)(qp + (w * 32 + m * 16 + l15) * 64 + kk * 32 + l4 * 8);

  float mst[2] = {-1e30f, -1e30f}, lst[2] = {0.f, 0.f};
  f32x4 oacc[2][4] = {};

  const int r = tid >> 2, c0 = (tid & 3) * 16;
  u16x8 kr0, kr1, vr0, vr1;
  {
    const unsigned short* kt = kp + tid * 16;
    kr0 = *(const u16x8*)kt; kr1 = *(const u16x8*)(kt + 8);
    const unsigned short* vt = vp + tid * 16;
    vr0 = *(const u16x8*)vt; vr1 = *(const u16x8*)(vt + 8);
  }

  for (int kb = 0; kb < 4; ++kb) {
    __syncthreads();
    {
      int bo = r * 128 + c0 * 2;
      *(u16x8*)((char*)Kl + swz(bo)) = kr0;
      *(u16x8*)((char*)Kl + swz(bo + 16)) = kr1;
#pragma unroll
      for (int j = 0; j < 8; ++j) {
        *(unsigned short*)((char*)Vt + swz((c0 + j) * 128 + r * 2)) = vr0[j];
        *(unsigned short*)((char*)Vt + swz((c0 + 8 + j) * 128 + r * 2)) = vr1[j];
      }
    }
    __syncthreads();
    if (kb < 3) {
      const unsigned short* kt = kp + (kb + 1) * (64 * kDk) + tid * 16;
      kr0 = *(const u16x8*)kt; kr1 = *(const u16x8*)(kt + 8);
      const unsigned short* vt = vp + (kb + 1) * (64 * kDk) + tid * 16;
      vr0 = *(const u16x8*)vt; vr1 = *(const u16x8*)(vt + 8);
    }

    f32x4 sacc[4][2] = {};
    __builtin_amdgcn_s_setprio(1);
#pragma unroll
    for (int kk = 0; kk < 2; ++kk) {
      bf16x8 kf[4];
#pragma unroll
      for (int kn = 0; kn < 4; ++kn) {
        int bo = (kn * 16 + l15) * 128 + (kk * 32 + l4 * 8) * 2;
        kf[kn] = *(const bf16x8*)((const char*)Kl + swz(bo));
      }
#pragma unroll
      for (int kn = 0; kn < 4; ++kn)
#pragma unroll
        for (int m = 0; m < 2; ++m)
          sacc[kn][m] = __builtin_amdgcn_mfma_f32_16x16x32_bf16(kf[kn], q[m][kk], sacc[kn][m], 0, 0, 0);
    }
    __builtin_amdgcn_s_setprio(0);

    unsigned pw[2][4][2];
    float cbq[2][4];
#pragma unroll
    for (int m = 0; m < 2; ++m) {
      float rm = -1e30f;
#pragma unroll
      for (int kn = 0; kn < 4; ++kn)
#pragma unroll
        for (int j = 0; j < 4; ++j) rm = fmaxf(rm, sacc[kn][m][j]);
      rm = fmaxf(rm, __shfl_xor(rm, 16, 64));
      rm = fmaxf(rm, __shfl_xor(rm, 32, 64));
      float mn = fmaxf(mst[m], rm);
      float corr = exp2f(mst[m] - mn);
      mst[m] = mn;
      float rs = 0.f;
#pragma unroll
      for (int kn = 0; kn < 4; ++kn) {
#pragma unroll
        for (int j = 0; j < 4; ++j) {
          float p = exp2f(sacc[kn][m][j] - mn);
          sacc[kn][m][j] = p;
          rs += p;
        }
        pw[m][kn][0] = cvtpk(sacc[kn][m][0], sacc[kn][m][1]);
        pw[m][kn][1] = cvtpk(sacc[kn][m][2], sacc[kn][m][3]);
      }
      rs += __shfl_xor(rs, 16, 64);
      rs += __shfl_xor(rs, 32, 64);
      lst[m] = lst[m] * corr + rs;
#pragma unroll
      for (int j = 0; j < 4; ++j) cbq[m][j] = __shfl(corr, l4 * 4 + j, 64);
#pragma unroll
      for (int n = 0; n < 4; ++n)
#pragma unroll
        for (int j = 0; j < 4; ++j) oacc[m][n][j] *= cbq[m][j];
    }

    __builtin_amdgcn_s_setprio(1);
#pragma unroll
    for (int kn = 0; kn < 4; ++kn) {
      bf16x4 vf[4];
#pragma unroll
      for (int n = 0; n < 4; ++n) {
        int bo = (n * 16 + l15) * 128 + (kn * 16 + l4 * 4) * 2;
        vf[n] = *(const bf16x4*)((const char*)Vt + swz(bo));
      }
#pragma unroll
      for (int m = 0; m < 2; ++m) {
        union { unsigned u[2]; bf16x4 h; } pk;
        pk.u[0] = pw[m][kn][0]; pk.u[1] = pw[m][kn][1];
#pragma unroll
        for (int n = 0; n < 4; ++n)
          oacc[m][n] = mfma16x16(pk.h, vf[n], oacc[m][n]);
      }
    }
    __builtin_amdgcn_s_setprio(0);
  }

  unsigned short* op = ow + base + (size_t)hf * 128 * kDk;
#pragma unroll
  for (int m = 0; m < 2; ++m) {
    float inv = 1.f / lst[m];
#pragma unroll
    for (int j = 0; j < 4; ++j) {
      float ib = __shfl(inv, l4 * 4 + j, 64);
      int srow = w * 32 + m * 16 + l4 * 4 + j;
#pragma unroll
      for (int n = 0; n < 4; ++n)
        op[(size_t)srow * 64 + n * 16 + l15] = f2bf(oacc[m][n][j] * ib);
    }
  }
}

}  // namespace

extern "C" void kernel_launch(void* const* d_in, const int* in_sizes, int n_in,
                              void* d_out, int out_size, void* d_ws, size_t ws_size,
                              hipStream_t stream) {
  const float* query = (const float*)d_in[0];
  const float* key   = (const float*)d_in[1];
  const float* value = (const float*)d_in[2];
  const float* Wq = (const float*)d_in[3];
  const float* bq = (const float*)d_in[4];
  const float* Wk = (const float*)d_in[5];
  const float* bk = (const float*)d_in[6];
  const float* Wv = (const float*)d_in[7];
  const float* bv = (const float*)d_in[8];
  const float* Wo = (const float*)d_in[9];
  const float* bo = (const float*)d_in[10];

  const float sQ = 0.125f * kLog2e;   // 1/sqrt(dk) * log2(e), folded into Q proj

  const size_t wsz = (size_t)kDm * kDm;          // 1M elems
  const size_t tsz = (size_t)kMr * kDm;          // 16M elems
  unsigned short* wsp = (unsigned short*)d_ws;
  unsigned short* wqb = wsp;                     // Wq|Wk|Wv|Wo contiguous
  unsigned short* wob = wqb + 3 * wsz;
  unsigned short* qws = wqb + 4 * wsz;
  unsigned short* kws = qws + tsz;
  unsigned short* vws = kws + tsz;
  unsigned short* aws = vws + tsz;

  const size_t need = (4 * wsz + 4 * tsz) * 2;   // 136 MB
  if (ws_size < need) return;

  cvt4<<<dim3(4096), dim3(256), 0, stream>>>(Wq, Wk, Wv, Wo, wqb);
  gemm_qkv8<<<dim3(768), dim3(1024), 0, stream>>>(query, key, value, wqb,
                                                  bq, bk, bv, qws, sQ);
  attn_blkdiag<<<dim3(2048), 256, 0, stream>>>(qws, kws, vws, aws);
  gemm_o8<<<dim3(256), dim3(512), 0, stream>>>(aws, wob, bo, (float*)d_out);
}